// Round 3
// baseline (118.516 us; speedup 1.0000x reference)
//
#include <hip/hip_runtime.h>

typedef _Float16 v8h __attribute__((ext_vector_type(8)));
typedef float v16f __attribute__((ext_vector_type(16)));

#define BB 8
#define NN 8192
#define MM 8192
#define SPLITM 8          // j-chunks per batch
#define CPTS 1024         // xyz2 points per chunk
#define JTC 32            // 32-point j-tiles per chunk
#define TPB 256           // 4 waves
#define NI 2              // i-tiles (B-frags) per wave
#define NPROD (BB * SPLITM * 32)  // 2048 producer blocks (round-0 structure, unchanged)
#define NMID (BB * 32)            // 256 consumer blocks (replaces chamfer_reduce)
#define MAGIC 0x13579BDFu         // can't collide with a constant-pattern poison fill

// Homogeneous K=16 encoding (k = (lane>>5)*8 + reg):
//  k=0..2 : A = yhat_c          B = -2*xhat_c
//  k=3,4  : A = (y2)_hi,(y2)_lo B = 1, 1
//  k=5,6  : A = 1, 1            B = (x2)_hi,(x2)_lo
//  k=7..15: B = 0  =>  A's k>=8 slots are DON'T-CARE -> A stored compressed;
//  all lanes read the khalf=0 frag (lane-pair same-addr broadcast, conflict-free).

__device__ __forceinline__ float min3f(float a, float b, float c) {
    return fminf(fminf(a, b), c);  // -> v_min3_f32
}

__global__ __launch_bounds__(TPB, 4) void chamfer_one(const float* __restrict__ xyz1,
                                                      const float* __restrict__ xyz2,
                                                      unsigned int* __restrict__ flags,
                                                      float* __restrict__ pmins,
                                                      float* __restrict__ out) {
    __shared__ v8h aLds[CPTS];  // 16 KB compressed A-frags (producers)
    __shared__ float ls[4];     // consumer cross-wave sums

    int bid = blockIdx.x;
    int t = threadIdx.x;

    if (bid < NPROD) {
        // ================= producer: byte-identical round-0 main =================
        int ig     = bid & 31;
        int jchunk = (bid >> 5) & 7;
        int b      = bid >> 8;
        int wid = t >> 6;
        int lane = t & 63;
        int laneq = lane & 31;
        int half = lane >> 5;

        // out-zero rides block 0's release chain: store -> fence -> flag[0];
        // every consumer polls flag[0] before its atomicAdd(out, ...)
        if (bid == 0 && t == 0) *(volatile float*)out = 0.0f;

        // ---- fused A pack: this chunk's 1024 xyz2 points, 4/thread ----
        const float* srcA = xyz2 + ((size_t)b * MM + (size_t)jchunk * CPTS) * 3;
#pragma unroll
        for (int k = 0; k < CPTS / TPB; ++k) {
            int p = k * TPB + t;
            float x = srcA[p * 3 + 0], y = srcA[p * 3 + 1], z = srcA[p * 3 + 2];
            _Float16 h0 = (_Float16)x, h1 = (_Float16)y, h2 = (_Float16)z;
            float y0 = (float)h0, y1 = (float)h1, y2v = (float)h2;
            float s = fmaf(y0, y0, fmaf(y1, y1, y2v * y2v));
            _Float16 shi = (_Float16)s;
            _Float16 slo = (_Float16)(s - (float)shi);
            v8h v = {h0, h1, h2, shi, slo, (_Float16)1.0f, (_Float16)1.0f, (_Float16)0.0f};
            aLds[p] = v;
        }

        // ---- fused B pack: this wave's two i-tiles (khalf=1 lanes stay zero) ----
        int it0 = (ig * 4 + wid) * NI;
        v8h bf[NI];
#pragma unroll
        for (int tt = 0; tt < NI; ++tt) {
            int i = (it0 + tt) * 32 + laneq;
            const float* p = xyz1 + ((size_t)b * NN + i) * 3;
            _Float16 h0 = (_Float16)p[0], h1 = (_Float16)p[1], h2 = (_Float16)p[2];
            float x0 = (float)h0, x1 = (float)h1, x2v = (float)h2;
            float s = fmaf(x0, x0, fmaf(x1, x1, x2v * x2v));
            _Float16 shi = (_Float16)s;
            _Float16 slo = (_Float16)(s - (float)shi);
            v8h v = {};
            if (half == 0) {
                v[0] = (_Float16)(-2.0f * x0);
                v[1] = (_Float16)(-2.0f * x1);
                v[2] = (_Float16)(-2.0f * x2v);
                v[3] = (_Float16)1.0f; v[4] = (_Float16)1.0f;
                v[5] = shi; v[6] = slo;
            }
            bf[tt] = v;
        }

        __syncthreads();

        const v16f zc = {};
        float mg[NI][4];
#pragma unroll
        for (int tt = 0; tt < NI; ++tt)
#pragma unroll
            for (int g = 0; g < 4; ++g) mg[tt][g] = 1e30f;

        int jt0 = wid * 8;
        v8h a_next = aLds[jt0 * 32 + laneq];
#pragma unroll 1
        for (int s = 0; s < JTC; ++s) {
            v8h a = a_next;
            int jn = ((s + 1) & (JTC - 1)) * 32;
            int jtn = (jn + jt0 * 32) & (CPTS - 1);
            a_next = aLds[jtn + laneq];
            v16f c[NI];
#pragma unroll
            for (int tt = 0; tt < NI; ++tt)
                c[tt] = __builtin_amdgcn_mfma_f32_32x32x16_f16(a, bf[tt], zc, 0, 0, 0);
#pragma unroll
            for (int tt = 0; tt < NI; ++tt)
#pragma unroll
                for (int g = 0; g < 4; ++g) {
                    int r = 4 * g;
                    mg[tt][g] = min3f(min3f(c[tt][r], c[tt][r + 1], c[tt][r + 2]),
                                      c[tt][r + 3], mg[tt][g]);
                }
        }

        float m0 = fminf(min3f(mg[0][0], mg[0][1], mg[0][2]), mg[0][3]);
        float m1 = fminf(min3f(mg[1][0], mg[1][1], mg[1][2]), mg[1][3]);
        m0 = fminf(m0, __shfl_xor(m0, 32));
        m1 = fminf(m1, __shfl_xor(m1, 32));
        int i = (it0 + half) * 32 + laneq;
        pmins[(size_t)jchunk * (BB * NN) + (size_t)b * NN + i] = half ? m1 : m0;

        // ---- publish: all stores drained at barrier, then device-scope release ----
        __syncthreads();
        if (t == 0) {
            __threadfence();
            atomicExch(&flags[bid], MAGIC);
        }
    } else {
        // ================= consumer: in-dispatch replacement for chamfer_reduce ===
        int m = bid - NPROD;  // 0..255, == old chamfer_reduce blockIdx
        int b = m >> 5;
        int ig = m & 31;

        // threads 0..7 poll the 8 producers of this i-slice; thread 8 polls
        // flag[0] (orders block 0's out-zero before our atomicAdd)
        if (t <= 8) {
            int pidx = (t == 8) ? 0 : (b * 256 + t * 32 + ig);
            while (atomicAdd(&flags[pidx], 0u) != MAGIC) __builtin_amdgcn_s_sleep(2);
        }
        __syncthreads();
        __threadfence();  // acquire: invalidate stale cached pmins lines

        int i = m * 256 + t;  // same mapping as old reduce kernel
        float v = pmins[i];
#pragma unroll
        for (int sp = 1; sp < SPLITM; ++sp)
            v = fminf(v, pmins[(size_t)sp * (BB * NN) + i]);
        float s = v;
#pragma unroll
        for (int off = 32; off > 0; off >>= 1) s += __shfl_down(s, off);
        int lane = t & 63, wv = t >> 6;
        if (lane == 0) ls[wv] = s;
        __syncthreads();
        if (t == 0) {
            float tt = (ls[0] + ls[1]) + (ls[2] + ls[3]);
            atomicAdd(out, tt * (1.0f / (float)(BB * NN)));
        }
    }
}

extern "C" void kernel_launch(void* const* d_in, const int* in_sizes, int n_in,
                              void* d_out, int out_size, void* d_ws, size_t ws_size,
                              hipStream_t stream) {
    const float* xyz1 = (const float*)d_in[0];
    const float* xyz2 = (const float*)d_in[1];
    float* out = (float*)d_out;
    unsigned int* flags = (unsigned int*)d_ws;            // 2048 x u32 = 8 KB
    float* pmins = (float*)((char*)d_ws + 8192);          // 2 MB partial mins

    chamfer_one<<<NPROD + NMID, TPB, 0, stream>>>(xyz1, xyz2, flags, pmins, out);
}